// Round 3
// baseline (663.230 us; speedup 1.0000x reference)
//
#include <hip/hip_runtime.h>

// AFM layer, MI355X gfx950.
// out[b] = sum_p attn_p * s_p,  s_p = sum_d x[i,d]x[j,d]p[d]
// One wave per batch, 25 MFMA iterations (780/800 pair-slots used):
//   Phase A: 32-triangle via circular rotation: t=1..15 all lanes (nl,(nl+t)&31),
//            t=16 lanes nl<16. prod symmetric -> pair order irrelevant, no mask.
//   Phase B: j=32..39 wave-uniform broadcast rows (8 iters, 256 pairs).
//   Phase C: 8-triangle of fields 32..39 (28 pairs, 1 iter, closed-form unrank).
// Logits via MFMA 32x32x16 f16: A=W1^T const frags, B=prod built in-register.
// b1 folded via MFMA C-operand chaining.
// LDS: stride-64 rows (NO padding) + XOR swizzle of 16B granules
//   (blk' = blk ^ (row&7)) -> 20,480 B/block = 8 blocks/CU = 32 waves/CU
//   (entire grid resident, zero tail) AND conflict-free ds_read_b128 frags.

typedef _Float16 f16;
typedef f16 f16x2 __attribute__((ext_vector_type(2)));
typedef f16 f16x8 __attribute__((ext_vector_type(8)));
typedef float fx16 __attribute__((ext_vector_type(16)));

#define NF 40
#define NB 8192

union V8 { f16x8 v8; f16x2 v2[4]; };

__global__ __launch_bounds__(256, 8) void afm_kernel(
    const float* __restrict__ x,   // [8192,40,64]
    const float* __restrict__ W1,  // [64,32]
    const float* __restrict__ b1,  // [32]
    const float* __restrict__ w2,  // [32]
    const float* __restrict__ p,   // [64]
    float* __restrict__ out)       // [8192]
{
    __shared__ f16 xh[4][NF * 64];   // 4 batches x 40 rows x 64 f16 = 20,480 B

    const int wid  = threadIdx.x >> 6;
    const int lane = threadIdx.x & 63;
    const int b    = blockIdx.x * 4 + wid;
    f16* Xs = &xh[wid][0];

    // ---- stage x[b] -> LDS f16, swizzled 16B granules, b128 writes ----
    // 320 granules of 8 f16; granule g of row r lands at blk = g ^ (r&7).
    const float4* xb = (const float4*)(x + (size_t)b * (NF * 64));
#pragma unroll
    for (int t = 0; t < 5; ++t) {
        int id = t * 64 + lane;                // granule id, 0..319
        float4 v0 = xb[id * 2];
        float4 v1 = xb[id * 2 + 1];
        f16x8 h = { (f16)v0.x, (f16)v0.y, (f16)v0.z, (f16)v0.w,
                    (f16)v1.x, (f16)v1.y, (f16)v1.z, (f16)v1.w };
        int row = id >> 3, g = id & 7;
        int blk = g ^ (row & 7);
        *(f16x8*)(Xs + (row << 6) + blk * 8) = h;   // 16B aligned
    }
    __syncthreads();

    const int nl = lane & 31;   // MFMA column / field index base
    const int hh = lane >> 5;   // wave half -> k sub-block + a-row group
    const int h8 = hh * 8;

    // ---- A-frags: W1^T, A[m=a][k=h8+j], d = kt*16 + h8 + j ----
    f16x8 w1f[4];
#pragma unroll
    for (int kt = 0; kt < 4; ++kt)
#pragma unroll
        for (int j = 0; j < 8; ++j)
            w1f[kt][j] = (f16)W1[(kt * 16 + h8 + j) * 32 + nl];

    // ---- p packed to match prod-frag element order (for fdot2) ----
    f16x2 pp[16];
#pragma unroll
    for (int kt = 0; kt < 4; ++kt)
#pragma unroll
        for (int m = 0; m < 4; ++m) {
            f16x2 t2 = { (f16)p[kt * 16 + h8 + 2 * m], (f16)p[kt * 16 + h8 + 2 * m + 1] };
            pp[kt * 4 + m] = t2;
        }

    // ---- b1 as persistent C-frag (row a = (r&3)+8*(r>>2)+4*hh), w2 per row ----
    fx16 b1C;
    float w2v[16];
#pragma unroll
    for (int r = 0; r < 16; ++r) {
        int a = (r & 3) + 8 * (r >> 2) + 4 * hh;
        b1C[r] = b1[a];
        w2v[r] = w2[a];
    }

    // ---- xi frags for row nl (held in regs for phases A+B) ----
    f16x8 xif[4];
    {
        int rb = nl & 7;
        const f16* rowp = Xs + (nl << 6);
#pragma unroll
        for (int kt = 0; kt < 4; ++kt) {
            int blk = (kt * 2 + hh) ^ rb;
            xif[kt] = *(const f16x8*)(rowp + blk * 8);
        }
    }

    float accW = 0.f, accWS = 0.f;

    auto body = [&](const f16x8* xi, int jrow, bool valid) {
        int rb = jrow & 7;
        const f16* rowp = Xs + (jrow << 6);
        V8 pr[4];
#pragma unroll
        for (int kt = 0; kt < 4; ++kt) {
            int blk = (kt * 2 + hh) ^ rb;
            f16x8 xj = *(const f16x8*)(rowp + blk * 8);   // ds_read_b128
            pr[kt].v8 = xi[kt] * xj;                       // v_pk_mul_f16 x4
        }
        // h = W1^T prod + b1 : chain C from persistent b1 frag
        fx16 C = __builtin_amdgcn_mfma_f32_32x32x16_f16(w1f[0], pr[0].v8, b1C, 0, 0, 0);
        C = __builtin_amdgcn_mfma_f32_32x32x16_f16(w1f[1], pr[1].v8, C, 0, 0, 0);
        C = __builtin_amdgcn_mfma_f32_32x32x16_f16(w1f[2], pr[2].v8, C, 0, 0, 0);
        C = __builtin_amdgcn_mfma_f32_32x32x16_f16(w1f[3], pr[3].v8, C, 0, 0, 0);
        // s_p partial over this half's 32 d's (fp32 accum)
        float sp = 0.f;
#pragma unroll
        for (int kt = 0; kt < 4; ++kt)
#pragma unroll
            for (int m = 0; m < 4; ++m)
                sp = __builtin_amdgcn_fdot2(pr[kt].v2[m], pp[kt * 4 + m], sp, false);
        // logit partial: relu(h)·w2 over this half's 16 a-rows (fp32, 2 trees)
        float l0 = 0.f, l1 = 0.f;
#pragma unroll
        for (int r = 0; r < 8; ++r) {
            l0 = fmaf(fmaxf(C[2 * r], 0.f),     w2v[2 * r],     l0);
            l1 = fmaf(fmaxf(C[2 * r + 1], 0.f), w2v[2 * r + 1], l1);
        }
        float l = l0 + l1;
        l  += __shfl_xor(l, 32);    // combine a-halves
        sp += __shfl_xor(sp, 32);   // combine k-halves
        float w = valid ? __expf(l) : 0.f;   // max-free softmax (|l| small)
        accW += w;
        accWS = fmaf(w, sp, accWS);
    };

    // Phase A: 32-triangle via rotation (t=1..15 full, t=16 half)
    for (int t = 1; t <= 16; ++t)
        body(xif, (nl + t) & 31, (t < 16) | (nl < 16));

    // Phase B: i = nl < 32 <= j, broadcast xj (wave-uniform row)
    for (int u = 0; u < 8; ++u)
        body(xif, 32 + u, true);

    // Phase C: 28 pairs among fields 32..39 (lanes nl<28)
    {
        int q = nl < 28 ? nl : 27;
        float disc = 225.0f - 8.0f * (float)q;
        int ii = (int)((15.0f - sqrtf(disc)) * 0.5f);
        if (ii * (15 - ii) / 2 > q) --ii;                 // sqrt 1-ulp fixups
        if ((ii + 1) * (14 - ii) / 2 <= q) ++ii;
        int jj = q - ii * (15 - ii) / 2 + ii + 1;
        int iC = 32 + ii, jC = 32 + jj;                   // pair (iC,jC), iC<jC
        f16x8 xi2[4];
        int rb = iC & 7;
        const f16* rowp = Xs + (iC << 6);
#pragma unroll
        for (int kt = 0; kt < 4; ++kt) {
            int blk = (kt * 2 + hh) ^ rb;
            xi2[kt] = *(const f16x8*)(rowp + blk * 8);
        }
        body(xi2, jC, nl < 28);
    }

    // reduce across the 32 columns (halves already identical)
#pragma unroll
    for (int m = 16; m >= 1; m >>= 1) {
        accW  += __shfl_xor(accW, m);
        accWS += __shfl_xor(accWS, m);
    }
    if (lane == 0) out[b] = accWS / accW;
}

extern "C" void kernel_launch(void* const* d_in, const int* in_sizes, int n_in,
                              void* d_out, int out_size, void* d_ws, size_t ws_size,
                              hipStream_t stream) {
    const float* x  = (const float*)d_in[0];
    const float* W1 = (const float*)d_in[1];
    const float* b1 = (const float*)d_in[2];
    const float* w2 = (const float*)d_in[3];
    const float* p  = (const float*)d_in[4];
    float* out = (float*)d_out;
    dim3 grid(NB / 4), block(256);
    hipLaunchKernelGGL(afm_kernel, grid, block, 0, stream, x, W1, b1, w2, p, out);
}

// Round 4
// 158.325 us; speedup vs baseline: 4.1890x; 4.1890x over previous
//
#include <hip/hip_runtime.h>

// AFM layer, MI355X gfx950.
// out[b] = sum_p attn_p * s_p,  s_p = sum_d x[i,d]x[j,d]p[d]
// One wave per batch, 25 MFMA iterations (780/800 pair-slots used):
//   Phase A: 32-triangle via circular rotation: t=1..15 all lanes (nl,(nl+t)&31),
//            t=16 lanes nl<16. prod symmetric -> pair order irrelevant, no mask.
//   Phase B: j=32..39 wave-uniform broadcast rows (8 iters, 256 pairs).
//   Phase C: 8-triangle of fields 32..39 (28 pairs, 1 iter, closed-form unrank).
// Logits via MFMA 32x32x16 f16: A=W1^T const frags, B=prod built in-register.
// b1 folded via MFMA C-operand chaining.
// LDS: stride-64 rows + XOR swizzle of 16B granules (blk' = blk ^ (row&7))
//   -> 20,480 B/block = 8 blocks/CU LDS-wise, single ds_read_b128 per frag.
// __launch_bounds__(256,4): R3 showed (256,8) strangles the allocator to
//   32 VGPR -> 2.1 GB scratch spill, 4.3x regression. (256,4) gives 64 VGPR
//   (measured R2) which still permits 8 waves/SIMD naturally.
// SQ_LDS_BANK_CONFLICT ~2.6/b128-read is pigeonhole-structural (1 KiB/wave
//   read > 2 conflict-free passes of 32 banks) — not actionable.

typedef _Float16 f16;
typedef f16 f16x2 __attribute__((ext_vector_type(2)));
typedef f16 f16x8 __attribute__((ext_vector_type(8)));
typedef float fx16 __attribute__((ext_vector_type(16)));

#define NF 40
#define NB 8192

union V8 { f16x8 v8; f16x2 v2[4]; };

__global__ __launch_bounds__(256, 4) void afm_kernel(
    const float* __restrict__ x,   // [8192,40,64]
    const float* __restrict__ W1,  // [64,32]
    const float* __restrict__ b1,  // [32]
    const float* __restrict__ w2,  // [32]
    const float* __restrict__ p,   // [64]
    float* __restrict__ out)       // [8192]
{
    __shared__ f16 xh[4][NF * 64];   // 4 batches x 40 rows x 64 f16 = 20,480 B

    const int wid  = threadIdx.x >> 6;
    const int lane = threadIdx.x & 63;
    const int b    = blockIdx.x * 4 + wid;
    f16* Xs = &xh[wid][0];

    // ---- stage x[b] -> LDS f16, swizzled 16B granules, b128 writes ----
    // 320 granules of 8 f16; granule g of row r lands at blk = g ^ (r&7).
    const float4* xb = (const float4*)(x + (size_t)b * (NF * 64));
#pragma unroll
    for (int t = 0; t < 5; ++t) {
        int id = t * 64 + lane;                // granule id, 0..319
        float4 v0 = xb[id * 2];
        float4 v1 = xb[id * 2 + 1];
        f16x8 h = { (f16)v0.x, (f16)v0.y, (f16)v0.z, (f16)v0.w,
                    (f16)v1.x, (f16)v1.y, (f16)v1.z, (f16)v1.w };
        int row = id >> 3, g = id & 7;
        int blk = g ^ (row & 7);
        *(f16x8*)(Xs + (row << 6) + blk * 8) = h;   // 16B aligned
    }
    __syncthreads();

    const int nl = lane & 31;   // MFMA column / field index base
    const int hh = lane >> 5;   // wave half -> k sub-block + a-row group
    const int h8 = hh * 8;

    // ---- A-frags: W1^T, A[m=a][k=h8+j], d = kt*16 + h8 + j ----
    f16x8 w1f[4];
#pragma unroll
    for (int kt = 0; kt < 4; ++kt)
#pragma unroll
        for (int j = 0; j < 8; ++j)
            w1f[kt][j] = (f16)W1[(kt * 16 + h8 + j) * 32 + nl];

    // ---- p packed to match prod-frag element order (for fdot2) ----
    f16x2 pp[16];
#pragma unroll
    for (int kt = 0; kt < 4; ++kt)
#pragma unroll
        for (int m = 0; m < 4; ++m) {
            f16x2 t2 = { (f16)p[kt * 16 + h8 + 2 * m], (f16)p[kt * 16 + h8 + 2 * m + 1] };
            pp[kt * 4 + m] = t2;
        }

    // ---- b1 as persistent C-frag (row a = (r&3)+8*(r>>2)+4*hh), w2 per row ----
    fx16 b1C;
    float w2v[16];
#pragma unroll
    for (int r = 0; r < 16; ++r) {
        int a = (r & 3) + 8 * (r >> 2) + 4 * hh;
        b1C[r] = b1[a];
        w2v[r] = w2[a];
    }

    // ---- xi frags for row nl (held in regs for phases A+B) ----
    f16x8 xif[4];
    {
        int rb = nl & 7;
        const f16* rowp = Xs + (nl << 6);
#pragma unroll
        for (int kt = 0; kt < 4; ++kt) {
            int blk = (kt * 2 + hh) ^ rb;
            xif[kt] = *(const f16x8*)(rowp + blk * 8);
        }
    }

    float accW = 0.f, accWS = 0.f;

    // MASKED=false iterations have no per-lane validity select at all.
    auto body = [&](const f16x8* xi, int jrow, bool masked, bool valid) {
        int rb = jrow & 7;
        const f16* rowp = Xs + (jrow << 6);
        V8 pr[4];
#pragma unroll
        for (int kt = 0; kt < 4; ++kt) {
            int blk = (kt * 2 + hh) ^ rb;
            f16x8 xj = *(const f16x8*)(rowp + blk * 8);   // ds_read_b128
            pr[kt].v8 = xi[kt] * xj;                       // v_pk_mul_f16 x4
        }
        // h = W1^T prod + b1 : chain C from persistent b1 frag
        fx16 C = __builtin_amdgcn_mfma_f32_32x32x16_f16(w1f[0], pr[0].v8, b1C, 0, 0, 0);
        C = __builtin_amdgcn_mfma_f32_32x32x16_f16(w1f[1], pr[1].v8, C, 0, 0, 0);
        C = __builtin_amdgcn_mfma_f32_32x32x16_f16(w1f[2], pr[2].v8, C, 0, 0, 0);
        C = __builtin_amdgcn_mfma_f32_32x32x16_f16(w1f[3], pr[3].v8, C, 0, 0, 0);
        // s_p partial over this half's 32 d's (fp32 accum)
        float sp = 0.f;
#pragma unroll
        for (int kt = 0; kt < 4; ++kt)
#pragma unroll
            for (int m = 0; m < 4; ++m)
                sp = __builtin_amdgcn_fdot2(pr[kt].v2[m], pp[kt * 4 + m], sp, false);
        // logit partial: relu(h)·w2 over this half's 16 a-rows (fp32, 2 trees)
        float l0 = 0.f, l1 = 0.f;
#pragma unroll
        for (int r = 0; r < 8; ++r) {
            l0 = fmaf(fmaxf(C[2 * r], 0.f),     w2v[2 * r],     l0);
            l1 = fmaf(fmaxf(C[2 * r + 1], 0.f), w2v[2 * r + 1], l1);
        }
        float l = l0 + l1;
        l  += __shfl_xor(l, 32);    // combine a-halves
        sp += __shfl_xor(sp, 32);   // combine k-halves
        float w = __expf(l);        // max-free softmax (|l| small)
        if (masked && !valid) w = 0.f;
        accW += w;
        accWS = fmaf(w, sp, accWS);
    };

    // Phase A: 32-triangle via rotation (t=1..15 full, t=16 half)
    for (int t = 1; t <= 15; ++t)
        body(xif, (nl + t) & 31, false, true);
    body(xif, (nl + 16) & 31, true, nl < 16);

    // Phase B: i = nl < 32 <= j, broadcast xj (wave-uniform row)
    for (int u = 0; u < 8; ++u)
        body(xif, 32 + u, false, true);

    // Phase C: 28 pairs among fields 32..39 (lanes nl<28)
    {
        int q = nl < 28 ? nl : 27;
        float disc = 225.0f - 8.0f * (float)q;
        int ii = (int)((15.0f - sqrtf(disc)) * 0.5f);
        if (ii * (15 - ii) / 2 > q) --ii;                 // sqrt 1-ulp fixups
        if ((ii + 1) * (14 - ii) / 2 <= q) ++ii;
        int jj = q - ii * (15 - ii) / 2 + ii + 1;
        int iC = 32 + ii, jC = 32 + jj;                   // pair (iC,jC), iC<jC
        f16x8 xi2[4];
        int rb = iC & 7;
        const f16* rowp = Xs + (iC << 6);
#pragma unroll
        for (int kt = 0; kt < 4; ++kt) {
            int blk = (kt * 2 + hh) ^ rb;
            xi2[kt] = *(const f16x8*)(rowp + blk * 8);
        }
        body(xi2, jC, true, nl < 28);
    }

    // reduce across the 32 columns (halves already identical)
#pragma unroll
    for (int m = 16; m >= 1; m >>= 1) {
        accW  += __shfl_xor(accW, m);
        accWS += __shfl_xor(accWS, m);
    }
    if (lane == 0) out[b] = accWS / accW;
}

extern "C" void kernel_launch(void* const* d_in, const int* in_sizes, int n_in,
                              void* d_out, int out_size, void* d_ws, size_t ws_size,
                              hipStream_t stream) {
    const float* x  = (const float*)d_in[0];
    const float* W1 = (const float*)d_in[1];
    const float* b1 = (const float*)d_in[2];
    const float* w2 = (const float*)d_in[3];
    const float* p  = (const float*)d_in[4];
    float* out = (float*)d_out;
    dim3 grid(NB / 4), block(256);
    hipLaunchKernelGGL(afm_kernel, grid, block, 0, stream, x, W1, b1, w2, p, out);
}